// Round 1
// baseline (178.699 us; speedup 1.0000x reference)
//
#include <hip/hip_runtime.h>
#include <stdint.h>

// Problem constants: bs=16, Q=1024, P=8, D=256, Cin=64, H=W=128, Cout=256.

typedef __attribute__((ext_vector_type(8))) short short8;   // 8 bf16 (4 VGPR)
typedef __attribute__((ext_vector_type(4))) float f32x4;    // MFMA acc

__device__ __forceinline__ unsigned short f2bf(float f) {
  union { float f; unsigned int u; } v; v.f = f;
  unsigned int r = (v.u + 0x7FFFu + ((v.u >> 16) & 1u)) >> 16;  // RNE
  return (unsigned short)r;
}
__device__ __forceinline__ float bf2f(unsigned short h) {
  union { unsigned int u; float f; } v; v.u = ((unsigned int)h) << 16;
  return v.f;
}

// async global->LDS, 16B per lane; LDS dest must be wave-uniform (HW adds lane*16)
__device__ __forceinline__ void gload_lds16(const void* g, void* l) {
  __builtin_amdgcn_global_load_lds(
      (const __attribute__((address_space(1))) unsigned int*)g,
      (__attribute__((address_space(3))) unsigned int*)l, 16, 0, 0);
}

// ---------------------------------------------------------------------------
// K1: bev (16,64,128,128) f32 NCHW  ->  bev_nhwc (16,128,128,64) bf16
// one block per (b,y); LDS tile with XOR swizzle keyed on (ic>>3) so both the
// float4 writes and the strided column reads are conflict-free.
// ---------------------------------------------------------------------------
__global__ __launch_bounds__(256) void k1_transpose(const float* __restrict__ bev,
                                                    unsigned short* __restrict__ nhwc) {
  __shared__ __align__(16) float lds[64 * 32 * 4];  // [ic][slot][4] = 32KB
  const int b = blockIdx.x >> 7, y = blockIdx.x & 127;
  const int t = threadIdx.x;
  const float* src = bev + (size_t)(b * 64) * 16384 + y * 128;
#pragma unroll
  for (int k = 0; k < 8; ++k) {
    int chunk = k * 256 + t;            // 0..2047 : ic(64) x xq(32)
    int ic = chunk >> 5, xq = chunk & 31;
    float4 v = *(const float4*)(src + ic * 16384 + xq * 4);
    int slot = xq ^ (ic >> 3);
    *(float4*)&lds[(ic * 32 + slot) * 4] = v;
  }
  __syncthreads();
  unsigned short* dst = nhwc + (size_t)blockIdx.x * 8192;  // [x][ic]
#pragma unroll
  for (int k = 0; k < 4; ++k) {
    int co = k * 256 + t;               // 0..1023 : x(128) x icg(8)
    int x = co >> 3, icg = co & 7;
    int slot = (x >> 2) ^ icg;
    int w = x & 3;
    uint4 u;
    unsigned int* up = (unsigned int*)&u;
#pragma unroll
    for (int jj = 0; jj < 4; ++jj) {
      float v0 = lds[((icg * 8 + 2 * jj) * 32 + slot) * 4 + w];
      float v1 = lds[((icg * 8 + 2 * jj + 1) * 32 + slot) * 4 + w];
      up[jj] = (unsigned int)f2bf(v0) | ((unsigned int)f2bf(v1) << 16);
    }
    *(uint4*)(dst + x * 64 + icg * 8) = u;
  }
}

// ---------------------------------------------------------------------------
// K1b: pack weights to MFMA-B-fragment-friendly chunk layouts (bf16) + zeropage
//   wconv[o][g][oc][j] = conv_w[oc][g*8+j][o/3][o%3]      (9*8*256*8)
//   wout [g][d][j]     = out_w[d][g*8+j]                  (32*256*8)
// ---------------------------------------------------------------------------
__global__ __launch_bounds__(256) void k1b_pack(const float* __restrict__ conv_w,
                                                const float* __restrict__ out_w,
                                                unsigned short* __restrict__ wconv,
                                                unsigned short* __restrict__ wout,
                                                float* __restrict__ zp) {
  const int tid = blockIdx.x * 256 + threadIdx.x;  // 16384 threads
  for (int idx = tid; idx < 9 * 8 * 256 * 8; idx += 16384) {
    int j = idx & 7, oc = (idx >> 3) & 255, g = (idx >> 11) & 7, o = idx >> 14;
    wconv[idx] = f2bf(conv_w[(oc * 64 + g * 8 + j) * 9 + o]);
  }
  for (int idx = tid; idx < 32 * 256 * 8; idx += 16384) {
    int j = idx & 7, d = (idx >> 3) & 255, g = idx >> 11;
    wout[idx] = f2bf(out_w[d * 256 + g * 8 + j]);
  }
  if (tid < 64) zp[tid] = 0.0f;
}

// ---------------------------------------------------------------------------
// K2: 3x3 conv + bias + relu as implicit GEMM (bf16 MFMA 16x16x32).
// block = (b, y): C[pix 128][oc 256], K = 576 = 9 offsets x 64 ic.
// 4 waves, wave tile 64(M) x 128(N). LDS:
//   in chunks [dyr(3)][icg(8)][c(130)][8ic] : 3120*16B (halo cols + OOB -> zeropage)
//   w  chunks [g'(4)][oc(256)][8ic]         : 1024*16B at byte 49920, per K-step
// epilogue repack through LDS [128][264] bf16 -> coalesced dwordx4 stores.
// ---------------------------------------------------------------------------
__global__ __launch_bounds__(256, 2) void k2_conv(const unsigned short* __restrict__ nhwc,
                                                  const unsigned short* __restrict__ wconv,
                                                  const float* __restrict__ conv_b,
                                                  const float* __restrict__ zp,
                                                  unsigned short* __restrict__ value) {
  __shared__ __align__(16) char smem[67584];
  short8* lds8 = (short8*)smem;
  const int b = blockIdx.x >> 7, y = blockIdx.x & 127;
  const int t = threadIdx.x, wid = t >> 6, lane = t & 63;
  const int wm = wid >> 1, wn = wid & 1;
  const int m0 = wm * 64, n0 = wn * 128;
  const int g = lane >> 4, l15 = lane & 15;

  // ---- stage input rows y-1..y+1 (once per block) ----
  const unsigned short* bevb = nhwc + (size_t)b * (128 * 128 * 64);
  for (int i = wid; i < 49; i += 4) {            // 49 wave-issues x 64 chunks
    const int chunk = i * 64 + lane;
    const void* src = (const void*)zp;
    if (chunk < 3120) {
      const int dyr = chunk / 1040;
      const int rem = chunk - dyr * 1040;
      const int icg = rem / 130;
      const int c = rem - icg * 130;
      const int yy = y + dyr - 1;
      const int xx = c - 1;
      if (yy >= 0 && yy < 128 && xx >= 0 && xx < 128)
        src = (const void*)(bevb + ((yy * 128 + xx) * 64 + icg * 8));
    }
    gload_lds16(src, (void*)(smem + i * 1024));  // overrun past 3120 lands in w-buf, re-staged later
  }

  const f32x4 z4 = {0.f, 0.f, 0.f, 0.f};
  f32x4 acc[4][8];
#pragma unroll
  for (int mf = 0; mf < 4; ++mf)
#pragma unroll
    for (int nf = 0; nf < 8; ++nf) acc[mf][nf] = z4;

  const int aBase = g * 130 + m0 + l15 + 1;   // chunk idx base for A frags
  const int wBase = g * 256 + n0 + l15;       // chunk idx base into w-buf
  const short8* ldsW = lds8 + 3120;

#pragma unroll
  for (int o = 0; o < 9; ++o) {
    const int dyr = o / 3;
    const int dx = o % 3 - 1;
#pragma unroll
    for (int ich = 0; ich < 2; ++ich) {
      __syncthreads();                           // prev w-buf consumers done
      const unsigned short* wsrc = wconv + (o * 2048 + ich * 1024) * 8;
#pragma unroll
      for (int i = 0; i < 4; ++i) {
        const int issue = i * 4 + wid;
        gload_lds16(wsrc + (issue * 64 + lane) * 8, (void*)(smem + 49920 + issue * 1024));
      }
      __syncthreads();                           // staged (barrier drains vmcnt)
      short8 af[4];
      const int ab = aBase + dyr * 1040 + ich * 520 + dx;
#pragma unroll
      for (int mf = 0; mf < 4; ++mf) af[mf] = lds8[ab + mf * 16];
      short8 bfr[8];
#pragma unroll
      for (int nf = 0; nf < 8; ++nf) bfr[nf] = ldsW[wBase + nf * 16];
#pragma unroll
      for (int mf = 0; mf < 4; ++mf)
#pragma unroll
        for (int nf = 0; nf < 8; ++nf)
          acc[mf][nf] = __builtin_amdgcn_mfma_f32_16x16x32_bf16(af[mf], bfr[nf], acc[mf][nf], 0, 0, 0);
    }
  }

  // ---- epilogue: bias + relu -> bf16, repack via LDS, coalesced store ----
  __syncthreads();
  float cb[8];
#pragma unroll
  for (int nf = 0; nf < 8; ++nf) cb[nf] = conv_b[n0 + nf * 16 + l15];
  unsigned short* lout = (unsigned short*)smem;  // [128][264]
#pragma unroll
  for (int mf = 0; mf < 4; ++mf)
#pragma unroll
    for (int nf = 0; nf < 8; ++nf) {
      const int oc = n0 + nf * 16 + l15;
#pragma unroll
      for (int r = 0; r < 4; ++r) {
        const int x = m0 + mf * 16 + g * 4 + r;
        float v = acc[mf][nf][r] + cb[nf];
        v = v > 0.f ? v : 0.f;
        lout[x * 264 + oc] = f2bf(v);
      }
    }
  __syncthreads();
  unsigned short* vdst = value + (size_t)blockIdx.x * 32768;  // [x][oc]
#pragma unroll
  for (int i = 0; i < 16; ++i) {
    const int cid = i * 256 + t;
    const int row = cid >> 5, cc = cid & 31;
    *(uint4*)(vdst + row * 256 + cc * 8) = *(const uint4*)(smem + row * 528 + cc * 16);
  }
}

// ---------------------------------------------------------------------------
// K3: per-query softmax + bilinear grid-sample + P-weighted sum -> S bf16.
// one wave per (b,q); lane owns 4 channels.
// ---------------------------------------------------------------------------
__global__ __launch_bounds__(256) void k3_sample(const float* __restrict__ queries,
                                                 const float* __restrict__ traj,
                                                 const float* __restrict__ attn_w,
                                                 const float* __restrict__ attn_b,
                                                 const unsigned short* __restrict__ value,
                                                 unsigned short* __restrict__ S) {
  const int wid = threadIdx.x >> 6, lane = threadIdx.x & 63;
  const int qg = blockIdx.x * 4 + wid;           // 0..16383
  const int b = qg >> 10;
  const float4 qv = ((const float4*)queries)[qg * 64 + lane];
  float a[8];
#pragma unroll
  for (int p = 0; p < 8; ++p) {
    float4 wv = ((const float4*)attn_w)[p * 64 + lane];
    float d = qv.x * wv.x + qv.y * wv.y + qv.z * wv.z + qv.w * wv.w;
#pragma unroll
    for (int off = 32; off >= 1; off >>= 1) d += __shfl_xor(d, off);
    a[p] = d + attn_b[p];
  }
  float mx = a[0];
#pragma unroll
  for (int p = 1; p < 8; ++p) mx = fmaxf(mx, a[p]);
  float ssum = 0.f;
#pragma unroll
  for (int p = 0; p < 8; ++p) { a[p] = __expf(a[p] - mx); ssum += a[p]; }
  const float inv = 1.f / ssum;

  float acc0 = 0.f, acc1 = 0.f, acc2 = 0.f, acc3 = 0.f;
  const unsigned short* vb = value + (size_t)b * (128 * 128 * 256);
  const int coff = lane * 4;
#pragma unroll
  for (int p = 0; p < 8; ++p) {
    const float ty = traj[(qg * 8 + p) * 2 + 0];
    const float tx = traj[(qg * 8 + p) * 2 + 1];
    const float fx = (tx * 0.03125f + 1.f) * 64.f - 0.5f;   // grid x from traj[...,1]
    const float fy = (ty * 0.03125f + 1.f) * 64.f - 0.5f;   // grid y from traj[...,0]
    const float fx0 = floorf(fx), fy0 = floorf(fy);
    const int ix0 = (int)fx0, iy0 = (int)fy0;
    const float wx1 = fx - fx0, wx0 = 1.f - wx1;
    const float wy1 = fy - fy0, wy0 = 1.f - wy1;
    const float ap = a[p] * inv;
    const float cw[4] = {wx0 * wy0 * ap, wx1 * wy0 * ap, wx0 * wy1 * ap, wx1 * wy1 * ap};
    const int cx[4] = {ix0, ix0 + 1, ix0, ix0 + 1};
    const int cy[4] = {iy0, iy0, iy0 + 1, iy0 + 1};
#pragma unroll
    for (int cc = 0; cc < 4; ++cc) {
      if (cx[cc] >= 0 && cx[cc] < 128 && cy[cc] >= 0 && cy[cc] < 128) {  // wave-uniform
        const ushort4 v = *(const ushort4*)(vb + (cy[cc] * 128 + cx[cc]) * 256 + coff);
        acc0 += cw[cc] * bf2f(v.x);
        acc1 += cw[cc] * bf2f(v.y);
        acc2 += cw[cc] * bf2f(v.z);
        acc3 += cw[cc] * bf2f(v.w);
      }
    }
  }
  ushort4 o;
  o.x = f2bf(acc0); o.y = f2bf(acc1); o.z = f2bf(acc2); o.w = f2bf(acc3);
  *(ushort4*)(S + (size_t)qg * 256 + coff) = o;
}

// ---------------------------------------------------------------------------
// K4: out[q][d] = sum_c S[q][c]*out_w[d][c] + out_b[d] + queries[q][d]
// block = 128 q x 256 d, 4 waves (64x128 each), K=256 in 8 steps.
// ---------------------------------------------------------------------------
__global__ __launch_bounds__(256, 2) void k4_proj(const unsigned short* __restrict__ S,
                                                  const unsigned short* __restrict__ wout,
                                                  const float* __restrict__ out_b,
                                                  const float* __restrict__ queries,
                                                  float* __restrict__ out) {
  __shared__ __align__(16) char smem[8192];      // [g'(4)][q(128)][8c] chunks
  short8* lds8 = (short8*)smem;
  const int t = threadIdx.x, wid = t >> 6, lane = t & 63;
  const int wm = wid >> 1, wn = wid & 1;
  const int m0 = wm * 64, n0 = wn * 128;
  const int q0 = blockIdx.x * 128;
  const int g = lane >> 4, l15 = lane & 15;
  const f32x4 z4 = {0.f, 0.f, 0.f, 0.f};
  f32x4 acc[4][8];
#pragma unroll
  for (int mf = 0; mf < 4; ++mf)
#pragma unroll
    for (int nf = 0; nf < 8; ++nf) acc[mf][nf] = z4;
  const short8* wp = (const short8*)wout;
#pragma unroll
  for (int ks = 0; ks < 8; ++ks) {
    __syncthreads();
#pragma unroll
    for (int i = 0; i < 2; ++i) {
      const int issue = i * 4 + wid;
      const int chunk = issue * 64 + lane;
      const int gg = chunk >> 7, q = chunk & 127;
      gload_lds16(S + ((size_t)(q0 + q) * 256 + ks * 32 + gg * 8), (void*)(smem + issue * 1024));
    }
    __syncthreads();
    short8 af[4];
#pragma unroll
    for (int mf = 0; mf < 4; ++mf) af[mf] = lds8[g * 128 + m0 + mf * 16 + l15];
    short8 bfr[8];
#pragma unroll
    for (int nf = 0; nf < 8; ++nf) bfr[nf] = wp[(ks * 4 + g) * 256 + n0 + nf * 16 + l15];
#pragma unroll
    for (int mf = 0; mf < 4; ++mf)
#pragma unroll
      for (int nf = 0; nf < 8; ++nf)
        acc[mf][nf] = __builtin_amdgcn_mfma_f32_16x16x32_bf16(af[mf], bfr[nf], acc[mf][nf], 0, 0, 0);
  }
  float ob[8];
#pragma unroll
  for (int nf = 0; nf < 8; ++nf) ob[nf] = out_b[n0 + nf * 16 + l15];
#pragma unroll
  for (int mf = 0; mf < 4; ++mf)
#pragma unroll
    for (int nf = 0; nf < 8; ++nf) {
      const int d = n0 + nf * 16 + l15;
#pragma unroll
      for (int r = 0; r < 4; ++r) {
        const int gq = q0 + m0 + mf * 16 + g * 4 + r;
        out[(size_t)gq * 256 + d] = acc[mf][nf][r] + ob[nf] + queries[(size_t)gq * 256 + d];
      }
    }
}

// ---------------------------------------------------------------------------
extern "C" void kernel_launch(void* const* d_in, const int* in_sizes, int n_in,
                              void* d_out, int out_size, void* d_ws, size_t ws_size,
                              hipStream_t stream) {
  const float* queries = (const float*)d_in[0];
  const float* traj    = (const float*)d_in[1];
  const float* bev     = (const float*)d_in[2];
  // d_in[3] = spatial_shape (int64) — constant (128,128), unused
  const float* attn_w  = (const float*)d_in[4];
  const float* attn_b  = (const float*)d_in[5];
  const float* conv_w  = (const float*)d_in[6];
  const float* conv_b  = (const float*)d_in[7];
  const float* out_w   = (const float*)d_in[8];
  const float* out_b   = (const float*)d_in[9];
  float* out = (float*)d_out;

  char* ws = (char*)d_ws;
  unsigned short* bev_nhwc = (unsigned short*)(ws);               //  33,554,432 B
  unsigned short* value    = (unsigned short*)(ws + 33554432);    // 134,217,728 B
  unsigned short* wconv    = (unsigned short*)(ws + 167772160);   //     294,912 B
  unsigned short* wout     = (unsigned short*)(ws + 168067072);   //     131,072 B
  unsigned short* Sbuf     = (unsigned short*)(ws + 168198144);   //   8,388,608 B
  float*          zp       = (float*)(ws + 176586752);            //         256 B

  k1_transpose<<<2048, 256, 0, stream>>>(bev, bev_nhwc);
  k1b_pack<<<64, 256, 0, stream>>>(conv_w, out_w, wconv, wout, zp);
  k2_conv<<<2048, 256, 0, stream>>>(bev_nhwc, wconv, conv_b, zp, value);
  k3_sample<<<4096, 256, 0, stream>>>(queries, traj, attn_w, attn_b, value, Sbuf);
  k4_proj<<<128, 256, 0, stream>>>(Sbuf, wout, out_b, queries, out);
}

// Round 2
// 173.802 us; speedup vs baseline: 1.0282x; 1.0282x over previous
//
#include <hip/hip_runtime.h>
#include <stdint.h>

// Problem constants: bs=16, Q=1024, P=8, D=256, Cin=64, H=W=128, Cout=256.

typedef __attribute__((ext_vector_type(8))) short short8;   // 8 bf16 (4 VGPR)
typedef __attribute__((ext_vector_type(4))) float f32x4;    // MFMA acc

__device__ __forceinline__ unsigned short f2bf(float f) {
  union { float f; unsigned int u; } v; v.f = f;
  unsigned int r = (v.u + 0x7FFFu + ((v.u >> 16) & 1u)) >> 16;  // RNE
  return (unsigned short)r;
}
__device__ __forceinline__ float bf2f(unsigned short h) {
  union { unsigned int u; float f; } v; v.u = ((unsigned int)h) << 16;
  return v.f;
}

// async global->LDS, 16B per lane; LDS dest wave-uniform (HW adds lane*16),
// global src per-lane.
__device__ __forceinline__ void gload_lds16(const void* g, void* l) {
  __builtin_amdgcn_global_load_lds(
      (const __attribute__((address_space(1))) unsigned int*)g,
      (__attribute__((address_space(3))) unsigned int*)l, 16, 0, 0);
}

// ---------------------------------------------------------------------------
// K1: bev (16,64,128,128) f32 NCHW -> bev_nhwc (16,128,128,64) bf16 (unchanged)
// ---------------------------------------------------------------------------
__global__ __launch_bounds__(256) void k1_transpose(const float* __restrict__ bev,
                                                    unsigned short* __restrict__ nhwc) {
  __shared__ __align__(16) float lds[64 * 32 * 4];
  const int b = blockIdx.x >> 7, y = blockIdx.x & 127;
  const int t = threadIdx.x;
  const float* src = bev + (size_t)(b * 64) * 16384 + y * 128;
#pragma unroll
  for (int k = 0; k < 8; ++k) {
    int chunk = k * 256 + t;
    int ic = chunk >> 5, xq = chunk & 31;
    float4 v = *(const float4*)(src + ic * 16384 + xq * 4);
    int slot = xq ^ (ic >> 3);
    *(float4*)&lds[(ic * 32 + slot) * 4] = v;
  }
  __syncthreads();
  unsigned short* dst = nhwc + (size_t)blockIdx.x * 8192;
#pragma unroll
  for (int k = 0; k < 4; ++k) {
    int co = k * 256 + t;
    int x = co >> 3, icg = co & 7;
    int slot = (x >> 2) ^ icg;
    int w = x & 3;
    uint4 u;
    unsigned int* up = (unsigned int*)&u;
#pragma unroll
    for (int jj = 0; jj < 4; ++jj) {
      float v0 = lds[((icg * 8 + 2 * jj) * 32 + slot) * 4 + w];
      float v1 = lds[((icg * 8 + 2 * jj + 1) * 32 + slot) * 4 + w];
      up[jj] = (unsigned int)f2bf(v0) | ((unsigned int)f2bf(v1) << 16);
    }
    *(uint4*)(dst + x * 64 + icg * 8) = u;
  }
}

// ---------------------------------------------------------------------------
// K1b: pack weights (unchanged layouts)
//   wconv[o][gg8][oc256][j8] = conv_w[oc][gg*8+j][o/3][o%3]
//   wout [cg32][d256][j8]    = out_w[d][cg*8+j]
// ---------------------------------------------------------------------------
__global__ __launch_bounds__(256) void k1b_pack(const float* __restrict__ conv_w,
                                                const float* __restrict__ out_w,
                                                unsigned short* __restrict__ wconv,
                                                unsigned short* __restrict__ wout,
                                                float* __restrict__ zp) {
  const int tid = blockIdx.x * 256 + threadIdx.x;
  for (int idx = tid; idx < 9 * 8 * 256 * 8; idx += 16384) {
    int j = idx & 7, oc = (idx >> 3) & 255, g = (idx >> 11) & 7, o = idx >> 14;
    wconv[idx] = f2bf(conv_w[(oc * 64 + g * 8 + j) * 9 + o]);
  }
  for (int idx = tid; idx < 32 * 256 * 8; idx += 16384) {
    int j = idx & 7, d = (idx >> 3) & 255, g = idx >> 11;
    wout[idx] = f2bf(out_w[d * 256 + g * 8 + j]);
  }
  if (tid < 64) zp[tid] = 0.0f;
}

// ---------------------------------------------------------------------------
// K2 v2: 3x3 conv + bias + relu, implicit GEMM, SWAPPED operands:
//   D[oc][pix] = sum_k  W[oc][k] * In[k][pix]
// block = (b, row-pair): 256 pix x 256 oc, 512 threads = 8 waves (2 oc x 4 pix),
// wave tile 128 oc x 64 pix, acc[8][4], K = 576 in 18 steps of 32.
// LDS: input 4 rows [ridx4][icg8][c130] chunks (66,560B) staged once;
//      weights double-buffered 2 x 16KB (one half-offset per step).
// One __syncthreads per K-step (T3-minimum 2-phase: stage s+1 issued before
// compute s, barrier's vmcnt(0) drain lands after the compute phase).
// Epilogue: thread holds 4 consecutive oc -> direct ushort4 global stores.
// ---------------------------------------------------------------------------
#define K2_WOFF 66560
__global__ __launch_bounds__(512, 2) void k2_conv(const unsigned short* __restrict__ nhwc,
                                                  const unsigned short* __restrict__ wconv,
                                                  const float* __restrict__ conv_b,
                                                  const float* __restrict__ zp,
                                                  unsigned short* __restrict__ value) {
  __shared__ __align__(16) char smem[99328];   // 66560 input + 2*16384 weights
  const short8* lin = (const short8*)smem;
  const int bid = blockIdx.x;
  const int swz = (bid & 7) * 128 + (bid >> 3);    // XCD swizzle: 2 images/XCD
  const int b = swz >> 6, yp = swz & 63;
  const int y0 = yp * 2;
  const int t = threadIdx.x, wid = t >> 6, lane = t & 63;
  const int wo = wid >> 2, wp = wid & 3;           // oc-half, pix-quarter
  const int g = lane >> 4, l15 = lane & 15;
  const int r_hat = wp >> 1;                       // row within pair
  const int xbase = (wp & 1) * 64 + l15;           // wave's pixel column base

  // ---- prologue: stage input rows y0-1 .. y0+2 (4160 chunks = 65 issues) ----
  const unsigned short* bevb = nhwc + (size_t)b * (128 * 128 * 64);
  for (int i = wid; i < 65; i += 8) {
    const int chunk = i * 64 + lane;
    const int ridx = chunk / 1040;
    const int rem = chunk - ridx * 1040;
    const int icg = rem / 130;
    const int c = rem - icg * 130;
    const int yy = y0 - 1 + ridx, xx = c - 1;
    const void* src = (yy >= 0 && yy < 128 && xx >= 0 && xx < 128)
                          ? (const void*)(bevb + ((yy * 128 + xx) * 64 + icg * 8))
                          : (const void*)zp;
    gload_lds16(src, smem + i * 1024);
  }
  // stage weights for step 0 into buf 0 (2 issues/wave, 16 total)
  {
    const unsigned short* wsrc = wconv;            // o=0, ich=0
    gload_lds16(wsrc + (size_t)(wid * 128 + lane) * 8, smem + K2_WOFF + wid * 2048);
    gload_lds16(wsrc + (size_t)(wid * 128 + 64 + lane) * 8, smem + K2_WOFF + wid * 2048 + 1024);
  }
  __syncthreads();

  const f32x4 z4 = {0.f, 0.f, 0.f, 0.f};
  f32x4 acc[8][4];
#pragma unroll
  for (int i = 0; i < 8; ++i)
#pragma unroll
    for (int j = 0; j < 4; ++j) acc[i][j] = z4;

#pragma unroll
  for (int s = 0; s < 18; ++s) {
    const int o = s >> 1, ich = s & 1;
    const int dyr = o / 3;
    const int dx = o - dyr * 3 - 1;
    // ---- stage next half-offset into the other buffer ----
    if (s < 17) {
      const int s1 = s + 1;
      const unsigned short* wsrc = wconv + (size_t)(((s1 >> 1) * 2048 + (s1 & 1) * 1024)) * 8;
      char* wdst = smem + K2_WOFF + ((s1 & 1) ? 16384 : 0) + wid * 2048;
      gload_lds16(wsrc + (size_t)(wid * 128 + lane) * 8, wdst);
      gload_lds16(wsrc + (size_t)(wid * 128 + 64 + lane) * 8, wdst + 1024);
    }
    // ---- A-frags: weights [oc rows] ----
    const short8* wb = (const short8*)(smem + K2_WOFF + ((s & 1) ? 16384 : 0));
    short8 af[8];
#pragma unroll
    for (int ocf = 0; ocf < 8; ++ocf) af[ocf] = wb[g * 256 + wo * 128 + ocf * 16 + l15];
    // ---- B-frags: pixels [k][pix cols] ----
    short8 bf[4];
    const int cb = ((r_hat + dyr) * 8 + ich * 4 + g) * 130 + xbase + 1 + dx;
#pragma unroll
    for (int pf = 0; pf < 4; ++pf) bf[pf] = lin[cb + pf * 16];
    __builtin_amdgcn_s_setprio(1);
#pragma unroll
    for (int ocf = 0; ocf < 8; ++ocf)
#pragma unroll
      for (int pf = 0; pf < 4; ++pf)
        acc[ocf][pf] = __builtin_amdgcn_mfma_f32_16x16x32_bf16(af[ocf], bf[pf], acc[ocf][pf], 0, 0, 0);
    __builtin_amdgcn_s_setprio(0);
    __syncthreads();
  }

  // ---- epilogue: bias + relu -> direct ushort4 stores (4 consecutive oc) ----
  const int y = y0 + r_hat;
  unsigned short* vrow = value + (((size_t)(b * 128 + y) * 128 + xbase) * 256);
#pragma unroll
  for (int ocf = 0; ocf < 8; ++ocf) {
    const int ocb = wo * 128 + ocf * 16 + g * 4;
    const float4 cb4 = *(const float4*)(conv_b + ocb);
#pragma unroll
    for (int pf = 0; pf < 4; ++pf) {
      ushort4 ov;
      float v0 = acc[ocf][pf][0] + cb4.x; ov.x = f2bf(v0 > 0.f ? v0 : 0.f);
      float v1 = acc[ocf][pf][1] + cb4.y; ov.y = f2bf(v1 > 0.f ? v1 : 0.f);
      float v2 = acc[ocf][pf][2] + cb4.z; ov.z = f2bf(v2 > 0.f ? v2 : 0.f);
      float v3 = acc[ocf][pf][3] + cb4.w; ov.w = f2bf(v3 > 0.f ? v3 : 0.f);
      *(ushort4*)(vrow + (size_t)pf * 16 * 256 + ocb) = ov;
    }
  }
}

// ---------------------------------------------------------------------------
// K3: per-query softmax + bilinear grid-sample + P-weighted sum (unchanged)
// ---------------------------------------------------------------------------
__global__ __launch_bounds__(256) void k3_sample(const float* __restrict__ queries,
                                                 const float* __restrict__ traj,
                                                 const float* __restrict__ attn_w,
                                                 const float* __restrict__ attn_b,
                                                 const unsigned short* __restrict__ value,
                                                 unsigned short* __restrict__ S) {
  const int wid = threadIdx.x >> 6, lane = threadIdx.x & 63;
  const int qg = blockIdx.x * 4 + wid;
  const int b = qg >> 10;
  const float4 qv = ((const float4*)queries)[qg * 64 + lane];
  float a[8];
#pragma unroll
  for (int p = 0; p < 8; ++p) {
    float4 wv = ((const float4*)attn_w)[p * 64 + lane];
    float d = qv.x * wv.x + qv.y * wv.y + qv.z * wv.z + qv.w * wv.w;
#pragma unroll
    for (int off = 32; off >= 1; off >>= 1) d += __shfl_xor(d, off);
    a[p] = d + attn_b[p];
  }
  float mx = a[0];
#pragma unroll
  for (int p = 1; p < 8; ++p) mx = fmaxf(mx, a[p]);
  float ssum = 0.f;
#pragma unroll
  for (int p = 0; p < 8; ++p) { a[p] = __expf(a[p] - mx); ssum += a[p]; }
  const float inv = 1.f / ssum;

  float acc0 = 0.f, acc1 = 0.f, acc2 = 0.f, acc3 = 0.f;
  const unsigned short* vb = value + (size_t)b * (128 * 128 * 256);
  const int coff = lane * 4;
#pragma unroll
  for (int p = 0; p < 8; ++p) {
    const float ty = traj[(qg * 8 + p) * 2 + 0];
    const float tx = traj[(qg * 8 + p) * 2 + 1];
    const float fx = (tx * 0.03125f + 1.f) * 64.f - 0.5f;
    const float fy = (ty * 0.03125f + 1.f) * 64.f - 0.5f;
    const float fx0 = floorf(fx), fy0 = floorf(fy);
    const int ix0 = (int)fx0, iy0 = (int)fy0;
    const float wx1 = fx - fx0, wx0 = 1.f - wx1;
    const float wy1 = fy - fy0, wy0 = 1.f - wy1;
    const float ap = a[p] * inv;
    const float cw[4] = {wx0 * wy0 * ap, wx1 * wy0 * ap, wx0 * wy1 * ap, wx1 * wy1 * ap};
    const int cx[4] = {ix0, ix0 + 1, ix0, ix0 + 1};
    const int cy[4] = {iy0, iy0, iy0 + 1, iy0 + 1};
#pragma unroll
    for (int cc = 0; cc < 4; ++cc) {
      if (cx[cc] >= 0 && cx[cc] < 128 && cy[cc] >= 0 && cy[cc] < 128) {
        const ushort4 v = *(const ushort4*)(vb + (cy[cc] * 128 + cx[cc]) * 256 + coff);
        acc0 += cw[cc] * bf2f(v.x);
        acc1 += cw[cc] * bf2f(v.y);
        acc2 += cw[cc] * bf2f(v.z);
        acc3 += cw[cc] * bf2f(v.w);
      }
    }
  }
  ushort4 o;
  o.x = f2bf(acc0); o.y = f2bf(acc1); o.z = f2bf(acc2); o.w = f2bf(acc3);
  *(ushort4*)(S + (size_t)qg * 256 + coff) = o;
}

// ---------------------------------------------------------------------------
// K4 v2: out[q][d] = S[q][:] . out_w[d][:] + out_b[d] + queries[q][d]
// swapped operands: D[d][q]; thread holds 4 consecutive d -> float4 stores.
// block = 128 q x 256 d, 4 waves (128d x 64q), S staged dbuf, wout from L2.
// ---------------------------------------------------------------------------
__global__ __launch_bounds__(256, 2) void k4_proj(const unsigned short* __restrict__ S,
                                                  const unsigned short* __restrict__ wout,
                                                  const float* __restrict__ out_b,
                                                  const float* __restrict__ queries,
                                                  float* __restrict__ out) {
  __shared__ __align__(16) char smem[16384];     // 2 x 512 chunks [gg4][q128]
  const short8* lds8 = (const short8*)smem;
  const short8* wp8 = (const short8*)wout;
  const int t = threadIdx.x, wid = t >> 6, lane = t & 63;
  const int wo = wid >> 1, wq = wid & 1;         // d-half, q-half
  const int q0 = blockIdx.x * 128;
  const int g = lane >> 4, l15 = lane & 15;
  const f32x4 z4 = {0.f, 0.f, 0.f, 0.f};
  f32x4 acc[8][4];
#pragma unroll
  for (int i = 0; i < 8; ++i)
#pragma unroll
    for (int j = 0; j < 4; ++j) acc[i][j] = z4;

  // stage ks=0
#pragma unroll
  for (int ii = 0; ii < 2; ++ii) {
    const int chunk = wid * 128 + ii * 64 + lane;
    const int gg = chunk >> 7, q = chunk & 127;
    gload_lds16(S + ((size_t)(q0 + q) * 256 + gg * 8), smem + wid * 2048 + ii * 1024);
  }
  __syncthreads();

#pragma unroll
  for (int ks = 0; ks < 8; ++ks) {
    if (ks < 7) {
      const int k1 = ks + 1;
#pragma unroll
      for (int ii = 0; ii < 2; ++ii) {
        const int chunk = wid * 128 + ii * 64 + lane;
        const int gg = chunk >> 7, q = chunk & 127;
        gload_lds16(S + ((size_t)(q0 + q) * 256 + k1 * 32 + gg * 8),
                    smem + ((k1 & 1) ? 8192 : 0) + wid * 2048 + ii * 1024);
      }
    }
    short8 af[8];
#pragma unroll
    for (int df = 0; df < 8; ++df)
      af[df] = wp8[(ks * 4 + g) * 256 + wo * 128 + df * 16 + l15];
    short8 bf[4];
    const short8* sb = lds8 + ((ks & 1) ? 512 : 0);
#pragma unroll
    for (int qf = 0; qf < 4; ++qf) bf[qf] = sb[g * 128 + wq * 64 + qf * 16 + l15];
    __builtin_amdgcn_s_setprio(1);
#pragma unroll
    for (int df = 0; df < 8; ++df)
#pragma unroll
      for (int qf = 0; qf < 4; ++qf)
        acc[df][qf] = __builtin_amdgcn_mfma_f32_16x16x32_bf16(af[df], bf[qf], acc[df][qf], 0, 0, 0);
    __builtin_amdgcn_s_setprio(0);
    __syncthreads();
  }

#pragma unroll
  for (int df = 0; df < 8; ++df) {
    const int db = wo * 128 + df * 16 + g * 4;
    const float4 ob4 = *(const float4*)(out_b + db);
#pragma unroll
    for (int qf = 0; qf < 4; ++qf) {
      const int q = q0 + wq * 64 + qf * 16 + l15;
      const float4 qv = *(const float4*)(queries + (size_t)q * 256 + db);
      float4 ov;
      ov.x = acc[df][qf][0] + ob4.x + qv.x;
      ov.y = acc[df][qf][1] + ob4.y + qv.y;
      ov.z = acc[df][qf][2] + ob4.z + qv.z;
      ov.w = acc[df][qf][3] + ob4.w + qv.w;
      *(float4*)(out + (size_t)q * 256 + db) = ov;
    }
  }
}

// ---------------------------------------------------------------------------
extern "C" void kernel_launch(void* const* d_in, const int* in_sizes, int n_in,
                              void* d_out, int out_size, void* d_ws, size_t ws_size,
                              hipStream_t stream) {
  const float* queries = (const float*)d_in[0];
  const float* traj    = (const float*)d_in[1];
  const float* bev     = (const float*)d_in[2];
  const float* attn_w  = (const float*)d_in[4];
  const float* attn_b  = (const float*)d_in[5];
  const float* conv_w  = (const float*)d_in[6];
  const float* conv_b  = (const float*)d_in[7];
  const float* out_w   = (const float*)d_in[8];
  const float* out_b   = (const float*)d_in[9];
  float* out = (float*)d_out;

  char* ws = (char*)d_ws;
  unsigned short* bev_nhwc = (unsigned short*)(ws);               //  33,554,432 B
  unsigned short* value    = (unsigned short*)(ws + 33554432);    // 134,217,728 B
  unsigned short* wconv    = (unsigned short*)(ws + 167772160);   //     294,912 B
  unsigned short* wout     = (unsigned short*)(ws + 168067072);   //     131,072 B
  unsigned short* Sbuf     = (unsigned short*)(ws + 168198144);   //   8,388,608 B
  float*          zp       = (float*)(ws + 176586752);            //         256 B

  k1_transpose<<<2048, 256, 0, stream>>>(bev, bev_nhwc);
  k1b_pack<<<64, 256, 0, stream>>>(conv_w, out_w, wconv, wout, zp);
  k2_conv<<<1024, 512, 0, stream>>>(bev_nhwc, wconv, conv_b, zp, value);
  k3_sample<<<4096, 256, 0, stream>>>(queries, traj, attn_w, attn_b, value, Sbuf);
  k4_proj<<<128, 256, 0, stream>>>(Sbuf, wout, out_b, queries, out);
}